// Round 11
// baseline (188.045 us; speedup 1.0000x reference)
//
#include <hip/hip_runtime.h>
#include <math.h>

constexpr int SEQ  = 2048;
constexpr int HID  = 1024;
constexpr int MTOT = 4096;     // B*S
constexpr int BH   = 32;       // B*nh

typedef _Float16 f16;
typedef _Float16 f16x8 __attribute__((ext_vector_type(8)));
typedef float    f32x4 __attribute__((ext_vector_type(4)));

// async global->LDS, 16B per lane; lds dest = wave-uniform base + lane*16
__device__ __forceinline__ void gld16(const f16* g, f16* l) {
    __builtin_amdgcn_global_load_lds(
        (__attribute__((address_space(1))) void*)g,
        (__attribute__((address_space(3))) void*)l, 16, 0, 0);
}

// ---------------------------------------------------------------------------
// prep: z=0: Wq-Wk -> WqkT, z=1: Wv -> WvT, z=2: Wo -> WoT  (transpose+f16)
//       z=3: x fp32 -> f16 flat copy
// ---------------------------------------------------------------------------
__global__ __launch_bounds__(256) void prep(const float* __restrict__ x,
                                            const float* __restrict__ Wq,
                                            const float* __restrict__ Wk,
                                            const float* __restrict__ Wv,
                                            const float* __restrict__ Wo,
                                            f16* __restrict__ xh,
                                            f16* __restrict__ WqkT,
                                            f16* __restrict__ WvT,
                                            f16* __restrict__ WoT) {
    __shared__ f16 T[64][72];
    const int z = blockIdx.z;
    const int t = threadIdx.x;

    if (z == 3) {
        const int chunk = blockIdx.y * 16 + blockIdx.x;
        const float* src = x + (size_t)chunk * 16384;
        f16* dst = xh + (size_t)chunk * 16384;
#pragma unroll
        for (int it = 0; it < 16; it++) {
            const int i = it * 1024 + t * 4;
            float4 v = *(const float4*)(src + i);
            f16 o[4] = {(f16)v.x, (f16)v.y, (f16)v.z, (f16)v.w};
            *(ushort4*)(dst + i) = *(ushort4*)o;
        }
        return;
    }

    const float* W  = (z == 0) ? Wq : (z == 1) ? Wv : Wo;
    f16* WT = (z == 0) ? WqkT : (z == 1) ? WvT : WoT;
    const int k0 = blockIdx.x * 64, n0 = blockIdx.y * 64;
    const int r  = t >> 4;
    const int c4 = (t & 15) * 4;
#pragma unroll
    for (int rr = 0; rr < 64; rr += 16) {
        float4 w = *(const float4*)(W + (size_t)(k0 + rr + r) * HID + n0 + c4);
        if (z == 0) {
            float4 w2 = *(const float4*)(Wk + (size_t)(k0 + rr + r) * HID + n0 + c4);
            w.x -= w2.x; w.y -= w2.y; w.z -= w2.z; w.w -= w2.w;
        }
        T[c4 + 0][rr + r] = (f16)w.x;
        T[c4 + 1][rr + r] = (f16)w.y;
        T[c4 + 2][rr + r] = (f16)w.z;
        T[c4 + 3][rr + r] = (f16)w.w;
    }
    __syncthreads();
#pragma unroll
    for (int pp = 0; pp < 2; pp++) {
        const int nr = pp * 32 + (t >> 3);
        const int kc = (t & 7) * 8;
        *(uint4*)(WT + (size_t)(n0 + nr) * HID + k0 + kc) = *(uint4*)(&T[nr][kc]);
    }
}

// ---------------------------------------------------------------------------
// Fused projection GEMM (dif + vT): 128x64 tile, global_load_lds staging with
// XOR-octet swizzle. Epilogues via LDS bounce for coalesced stores.
// ---------------------------------------------------------------------------
__global__ __launch_bounds__(256, 4) void proj_gemm(const f16* __restrict__ A,
                                                    const f16* __restrict__ WqkT,
                                                    const f16* __restrict__ WvT,
                                                    const float* __restrict__ bq,
                                                    const float* __restrict__ bk,
                                                    const float* __restrict__ bv,
                                                    f16* __restrict__ dif,
                                                    f16* __restrict__ vT) {
    __shared__ f16 As[128 * 72];
    __shared__ f16 Bs[64 * 64];
    const int t = threadIdx.x;
    const int m0  = blockIdx.x * 128;
    const int n0g = blockIdx.y * 64;
    const bool isv = (n0g >= HID);
    const f16* BT = isv ? WvT : WqkT;
    const int n0 = n0g & (HID - 1);
    const int w = t >> 6, l = t & 63, quad = l >> 4, ln = l & 15;
    const int wm = w * 32;
    const int xk = ln & 7;

    const int srow8 = l >> 3;
    const int soct  = (l & 7) ^ srow8;
    const f16* pa = A  + (size_t)(m0 + w * 32 + srow8) * HID + soct * 8;
    const f16* pb = BT + (size_t)(n0 + w * 16 + srow8) * HID + soct * 8;

    f32x4 acc[2][4] = {};

    for (int k0 = 0; k0 < HID; k0 += 64) {
        __syncthreads();
#pragma unroll
        for (int c = 0; c < 4; c++)
            gld16(pa + (size_t)c * 8 * HID + k0, As + (w * 4 + c) * 512);
#pragma unroll
        for (int c = 0; c < 2; c++)
            gld16(pb + (size_t)c * 8 * HID + k0, Bs + (w * 2 + c) * 512);
        __syncthreads();

#pragma unroll
        for (int kh = 0; kh < 2; kh++) {
            f16x8 af[2], bf[4];
#pragma unroll
            for (int mt = 0; mt < 2; mt++) {
                const int row = wm + mt * 16 + ln;
                const int oct = (kh * 4 + quad) ^ xk;
                af[mt] = *(const f16x8*)(As + row * 64 + oct * 8);
            }
#pragma unroll
            for (int nt = 0; nt < 4; nt++) {
                const int row = nt * 16 + ln;
                const int oct = (kh * 4 + quad) ^ xk;
                bf[nt] = *(const f16x8*)(Bs + row * 64 + oct * 8);
            }
#pragma unroll
            for (int mt = 0; mt < 2; mt++)
#pragma unroll
                for (int nt = 0; nt < 4; nt++)
                    acc[mt][nt] = __builtin_amdgcn_mfma_f32_16x16x32_f16(
                        af[mt], bf[nt], acc[mt][nt], 0, 0, 0);
        }
    }

    __syncthreads();
    const int b_  = m0 >> 11;
    const int s0g = m0 & 2047;
    const int h_  = n0 >> 6;

    if (!isv) {
        float bb[4];
#pragma unroll
        for (int nt = 0; nt < 4; nt++) {
            const int nl = n0 + nt * 16 + ln;
            bb[nt] = bq[nl] - bk[nl];
        }
#pragma unroll
        for (int mt = 0; mt < 2; mt++)
#pragma unroll
            for (int nt = 0; nt < 4; nt++)
#pragma unroll
                for (int r = 0; r < 4; r++) {
                    const int sl = wm + mt * 16 + quad * 4 + r;
                    As[sl * 72 + nt * 16 + ln] = (f16)(acc[mt][nt][r] + bb[nt]);
                }
        __syncthreads();
        f16* base = dif + ((size_t)(b_ * 16 + h_) * SEQ + s0g) * 64;
        const int sl = t >> 1, eo = (t & 1) * 32;
#pragma unroll
        for (int i = 0; i < 4; i++)
            *(uint4*)(base + (size_t)sl * 64 + eo + i * 8) =
                *(uint4*)(&As[sl * 72 + eo + i * 8]);
    } else {
        float bb[4];
#pragma unroll
        for (int nt = 0; nt < 4; nt++)
            bb[nt] = bv[n0 + nt * 16 + ln];
#pragma unroll
        for (int mt = 0; mt < 2; mt++)
#pragma unroll
            for (int nt = 0; nt < 4; nt++)
#pragma unroll
                for (int r = 0; r < 4; r++) {
                    const int sl = wm + mt * 16 + quad * 4 + r;
                    As[(nt * 16 + ln) * 136 + sl] = (f16)(acc[mt][nt][r] + bb[nt]);
                }
        __syncthreads();
        const int eb = t >> 2, so = (t & 3) * 32;
        f16* base = vT + ((size_t)(b_ * 16 + h_) * 64 + eb) * SEQ + s0g + so;
#pragma unroll
        for (int i = 0; i < 4; i++)
            *(uint4*)(base + i * 8) = *(uint4*)(&As[eb * 136 + so + i * 8]);
    }
}

// ---------------------------------------------------------------------------
// Output GEMM: out = (C0+C1) @ WoT^T * 65536 + bo. 128x64 tile, dbuf LDS.
// ---------------------------------------------------------------------------
__global__ __launch_bounds__(256) void out_gemm(const f16* __restrict__ C0,
                                                const f16* __restrict__ C1,
                                                const f16* __restrict__ WoT,
                                                const float* __restrict__ bo,
                                                float* __restrict__ out) {
    __shared__ f16 As[2][128 * 72];
    __shared__ f16 Bs[2][64 * 72];
    const int t = threadIdx.x;
    const int m0 = blockIdx.x * 128, n0 = blockIdx.y * 64;
    const int w = t >> 6, l = t & 63, quad = l >> 4, ln = l & 15;
    const int wm = (w >> 1) * 64, wn = (w & 1) * 32;
    const int arow = t >> 1, ahalf = (t & 1) * 32;
    const int brow = t >> 2, boff = (t & 3) * 16;

    const f16* pa0 = C0  + (size_t)(m0 + arow) * HID + ahalf;
    const f16* pa1 = C1  + (size_t)(m0 + arow) * HID + ahalf;
    const f16* pb  = WoT + (size_t)(n0 + brow) * HID + boff;

    f16x8 a0 = *(const f16x8*)(pa0)      + *(const f16x8*)(pa1);
    f16x8 a1 = *(const f16x8*)(pa0 + 8)  + *(const f16x8*)(pa1 + 8);
    f16x8 a2 = *(const f16x8*)(pa0 + 16) + *(const f16x8*)(pa1 + 16);
    f16x8 a3 = *(const f16x8*)(pa0 + 24) + *(const f16x8*)(pa1 + 24);
    uint4 b0 = *(const uint4*)(pb), b1 = *(const uint4*)(pb + 8);

    f32x4 acc[4][2] = {};
    int buf = 0;

    for (int k0 = 0; k0 < HID; k0 += 64) {
        f16* da = As[buf] + arow * 72 + ahalf;
        *(f16x8*)(da)      = a0; *(f16x8*)(da + 8)  = a1;
        *(f16x8*)(da + 16) = a2; *(f16x8*)(da + 24) = a3;
        f16* db = Bs[buf] + brow * 72 + boff;
        *(uint4*)(db) = b0; *(uint4*)(db + 8) = b1;
        __syncthreads();
        if (k0 + 64 < HID) {
            const int kn = k0 + 64;
            a0 = *(const f16x8*)(pa0 + kn)      + *(const f16x8*)(pa1 + kn);
            a1 = *(const f16x8*)(pa0 + kn + 8)  + *(const f16x8*)(pa1 + kn + 8);
            a2 = *(const f16x8*)(pa0 + kn + 16) + *(const f16x8*)(pa1 + kn + 16);
            a3 = *(const f16x8*)(pa0 + kn + 24) + *(const f16x8*)(pa1 + kn + 24);
            b0 = *(const uint4*)(pb + kn); b1 = *(const uint4*)(pb + kn + 8);
        }
#pragma unroll
        for (int kh = 0; kh < 2; kh++) {
            f16x8 af[4], bf[2];
#pragma unroll
            for (int mt = 0; mt < 4; mt++)
                af[mt] = *(const f16x8*)(As[buf] + (wm + mt * 16 + ln) * 72 + kh * 32 + quad * 8);
#pragma unroll
            for (int nt = 0; nt < 2; nt++)
                bf[nt] = *(const f16x8*)(Bs[buf] + (wn + nt * 16 + ln) * 72 + kh * 32 + quad * 8);
#pragma unroll
            for (int mt = 0; mt < 4; mt++)
#pragma unroll
                for (int nt = 0; nt < 2; nt++)
                    acc[mt][nt] = __builtin_amdgcn_mfma_f32_16x16x32_f16(
                        af[mt], bf[nt], acc[mt][nt], 0, 0, 0);
        }
        buf ^= 1;
    }

#pragma unroll
    for (int mt = 0; mt < 4; mt++)
#pragma unroll
        for (int nt = 0; nt < 2; nt++) {
            const int n = n0 + wn + nt * 16 + ln;
            const float bb = bo[n];
            const int m_base = m0 + wm + mt * 16 + quad * 4;
#pragma unroll
            for (int r = 0; r < 4; r++)
                out[(size_t)(m_base + r) * HID + n] =
                    acc[mt][nt][r] * 65536.0f + bb;
        }
}

// ---------------------------------------------------------------------------
// fp16 MFMA attention R11: waves own (q-half, j-half) 32x32 sub-tiles.
// S^T = K.Q^T (operand swap) -> P stores are b64-vectorized; PV per j-half
// (K=32, one chunk); cross-jh partial reduction via LDS once per q-half.
// k-split x2, grid 16x32x2 = 1024 blocks = 4/CU, LDS 36.9 KB.
// ---------------------------------------------------------------------------
__global__ __launch_bounds__(256, 4) void attn_f16(const f16* __restrict__ dif,
                                                   const f16* __restrict__ vT,
                                                   f16* __restrict__ ctx0,
                                                   f16* __restrict__ ctx1) {
    __shared__ f16 Qs[64 * 72];
    __shared__ f16 Ks[64 * 72];
    __shared__ f16 Vs[64 * 72];
    __shared__ f16 Ps[64 * 72];

    const int pq = blockIdx.x, bh = blockIdx.y, ks = blockIdx.z;
    f16* Cout = ks ? ctx1 : ctx0;
    const f16* D  = dif + (size_t)bh * SEQ * 64;
    const f16* VT = vT  + (size_t)bh * 64 * SEQ;
    const int b = bh >> 4, h = bh & 15;
    const int t = threadIdx.x, w = t >> 6, l = t & 63, quad = l >> 4, ln = l & 15;
    const int qh = w >> 1, jh = w & 1;    // wave's q-half / j-half
    const int ve = t >> 2, vc = (t & 3) * 16;

    for (int half = 0; half < 2; half++) {
        const int qt = half ? (31 - pq) : pq;
        const int i0 = qt * 64;
        __syncthreads();   // prior half's LDS use complete

        // stage Q tile (64x64, pitch 72), pull this wave's 4 A/B-frags to regs
#pragma unroll
        for (int rr = 0; rr < 2; rr++) {
            const int o = rr * 2048 + t * 8;
            uint4 v = *(const uint4*)(D + i0 * 64 + o);
            *(uint4*)(Qs + (o >> 6) * 72 + (o & 63)) = v;
        }
        __syncthreads();
        f16x8 aq[2][2];   // [mt][kh]  rows qh*32+mt*16+ln
#pragma unroll
        for (int mt = 0; mt < 2; mt++)
#pragma unroll
            for (int kh = 0; kh < 2; kh++)
                aq[mt][kh] = *(const f16x8*)(Qs + (qh * 32 + mt * 16 + ln) * 72
                                             + kh * 32 + quad * 8);

        f32x4 acc[2][4] = {};   // [mt][nt(e)]
        const int kt0 = qt + ks;

        uint4 kr0, kr1, vr0, vr1;
        if (kt0 < 32) {
            const int j0 = kt0 * 64;
            kr0 = *(const uint4*)(D + j0 * 64 + t * 8);
            kr1 = *(const uint4*)(D + j0 * 64 + 2048 + t * 8);
            vr0 = *(const uint4*)(VT + (size_t)ve * SEQ + j0 + vc);
            vr1 = *(const uint4*)(VT + (size_t)ve * SEQ + j0 + vc + 8);
        }

        for (int kt = kt0; kt < 32; kt += 2) {
            const int j0 = kt * 64;
            __syncthreads();   // prev iter frag reads done

            {
                const int o0 = t * 8, o1 = 2048 + t * 8;
                *(uint4*)(Ks + (o0 >> 6) * 72 + (o0 & 63)) = kr0;
                *(uint4*)(Ks + (o1 >> 6) * 72 + (o1 & 63)) = kr1;
                *(uint4*)(Vs + ve * 72 + vc)     = vr0;
                *(uint4*)(Vs + ve * 72 + vc + 8) = vr1;
            }
            __syncthreads();

            if (kt + 2 < 32) {
                const int j2 = (kt + 2) * 64;
                kr0 = *(const uint4*)(D + j2 * 64 + t * 8);
                kr1 = *(const uint4*)(D + j2 * 64 + 2048 + t * 8);
                vr0 = *(const uint4*)(VT + (size_t)ve * SEQ + j2 + vc);
                vr1 = *(const uint4*)(VT + (size_t)ve * SEQ + j2 + vc + 8);
            }

            // ---- S^T = K . Q^T  (this wave's 32 j-rows x 32 q-cols) ----
            f32x4 st[2][2] = {};   // [nt(j 16-tile)][mt(q 16-tile)]
#pragma unroll
            for (int kh = 0; kh < 2; kh++)
#pragma unroll
                for (int nt = 0; nt < 2; nt++) {
                    f16x8 ak = *(const f16x8*)(Ks + (jh * 32 + nt * 16 + ln) * 72
                                               + kh * 32 + quad * 8);
#pragma unroll
                    for (int mt = 0; mt < 2; mt++)
                        st[nt][mt] = __builtin_amdgcn_mfma_f32_16x16x32_f16(
                            ak, aq[mt][kh], st[nt][mt], 0, 0, 0);
                }

            // ---- P = mask*exp(-0.5*s - 16ln2); b64 stores, A-layout rows ----
            const bool full = (kt > qt);
#pragma unroll
            for (int nt = 0; nt < 2; nt++)
#pragma unroll
                for (int mt = 0; mt < 2; mt++) {
                    const int gi = i0 + qh * 32 + mt * 16 + ln;
                    f16 pv4[4];
#pragma unroll
                    for (int r = 0; r < 4; r++) {
                        const int gj = j0 + jh * 32 + nt * 16 + quad * 4 + r;
                        float p = (full || (gj > gi))
                                      ? fminf(__expf(fmaf(st[nt][mt][r], -0.5f,
                                                          -11.090354888959125f)),
                                              60000.0f)
                                      : 0.0f;
                        pv4[r] = (f16)p;
                    }
                    *(double*)(Ps + (qh * 32 + mt * 16 + ln) * 72
                               + jh * 32 + nt * 16 + quad * 4) = *(double*)pv4;
                }
            // no barrier: P region (rows qh-strip x cols jh-half) is wave-private

            // ---- ctx += P(q, j-half) @ V(j-half, e)  (K=32, one chunk) ----
            {
                f16x8 bv[4];
#pragma unroll
                for (int nt = 0; nt < 4; nt++)
                    bv[nt] = *(const f16x8*)(Vs + (nt * 16 + ln) * 72
                                             + jh * 32 + quad * 8);
#pragma unroll
                for (int mt = 0; mt < 2; mt++) {
                    f16x8 ap = *(const f16x8*)(Ps + (qh * 32 + mt * 16 + ln) * 72
                                               + jh * 32 + quad * 8);
#pragma unroll
                    for (int nt = 0; nt < 4; nt++)
                        acc[mt][nt] = __builtin_amdgcn_mfma_f32_16x16x32_f16(
                            ap, bv[nt], acc[mt][nt], 0, 0, 0);
                }
            }
        }

        // ---- cross-jh reduction (f16 via Ps) + store partial ctx ----
        __syncthreads();   // all waves done reading/writing Ps as P
        if (jh == 1) {
#pragma unroll
            for (int mt = 0; mt < 2; mt++)
#pragma unroll
                for (int nt = 0; nt < 4; nt++)
#pragma unroll
                    for (int r = 0; r < 4; r++)
                        Ps[(qh * 32 + mt * 16 + quad * 4 + r) * 72 + nt * 16 + ln] =
                            (f16)acc[mt][nt][r];
        }
        __syncthreads();
        if (jh == 0) {
#pragma unroll
            for (int mt = 0; mt < 2; mt++)
#pragma unroll
                for (int nt = 0; nt < 4; nt++)
#pragma unroll
                    for (int r = 0; r < 4; r++) {
                        const int iloc = qh * 32 + mt * 16 + quad * 4 + r;
                        float v = acc[mt][nt][r]
                                + (float)Ps[iloc * 72 + nt * 16 + ln];
                        Cout[(size_t)(b * SEQ + i0 + iloc) * HID + h * 64
                             + nt * 16 + ln] = (f16)v;
                    }
        }
    }
}

// ---------------------------------------------------------------------------
extern "C" void kernel_launch(void* const* d_in, const int* in_sizes, int n_in,
                              void* d_out, int out_size, void* d_ws, size_t ws_size,
                              hipStream_t stream) {
    const float* x  = (const float*)d_in[0];
    const float* Wq = (const float*)d_in[1];
    const float* bq = (const float*)d_in[2];
    const float* Wk = (const float*)d_in[3];
    const float* bk = (const float*)d_in[4];
    const float* Wv = (const float*)d_in[5];
    const float* bv = (const float*)d_in[6];
    const float* Wo = (const float*)d_in[7];
    const float* bo = (const float*)d_in[8];
    float* out = (float*)d_out;

    char* ws = (char*)d_ws;
    f16* xh   = (f16*)(ws);               // 8 MB  [M][1024]
    f16* WqkT = (f16*)(ws + (8 << 20));   // 2 MB  [n][k]
    f16* WvT  = (f16*)(ws + (10 << 20));  // 2 MB
    f16* WoT  = (f16*)(ws + (12 << 20));  // 2 MB
    f16* dif  = (f16*)(ws + (14 << 20));  // 8 MB  [bh][s][64]
    f16* vT   = (f16*)(ws + (22 << 20));  // 8 MB  [bh][e][s]
    f16* ctx0 = (f16*)(ws + (30 << 20));  // 8 MB  partial (x 2^-16)
    f16* ctx1 = (f16*)(ws + (38 << 20));  // 8 MB  partial

    prep<<<dim3(16, 16, 4), 256, 0, stream>>>(x, Wq, Wk, Wv, Wo,
                                              xh, WqkT, WvT, WoT);
    proj_gemm<<<dim3(MTOT / 128, 32), 256, 0, stream>>>(xh, WqkT, WvT,
                                                        bq, bk, bv, dif, vT);
    attn_f16<<<dim3(16, BH, 2), 256, 0, stream>>>(dif, vT, ctx0, ctx1);
    out_gemm<<<dim3(MTOT / 128, 16), 256, 0, stream>>>(ctx0, ctx1, WoT, bo, out);
}

// Round 12
// 185.756 us; speedup vs baseline: 1.0123x; 1.0123x over previous
//
#include <hip/hip_runtime.h>
#include <math.h>

constexpr int SEQ  = 2048;
constexpr int HID  = 1024;
constexpr int MTOT = 4096;     // B*S
constexpr int BH   = 32;       // B*nh

typedef _Float16 f16;
typedef _Float16 f16x4 __attribute__((ext_vector_type(4)));
typedef _Float16 f16x8 __attribute__((ext_vector_type(8)));
typedef float    f32x4 __attribute__((ext_vector_type(4)));

// async global->LDS, 16B per lane
__device__ __forceinline__ void gld16(const f16* g, f16* l) {
    __builtin_amdgcn_global_load_lds(
        (__attribute__((address_space(1))) void*)g,
        (__attribute__((address_space(3))) void*)l, 16, 0, 0);
}

// ---------------------------------------------------------------------------
// prep: z=0: Wq-Wk -> WqkT, z=1: Wv -> WvT, z=2: Wo -> WoT  (transpose+f16)
//       z=3: x fp32 -> f16 flat copy
// ---------------------------------------------------------------------------
__global__ __launch_bounds__(256) void prep(const float* __restrict__ x,
                                            const float* __restrict__ Wq,
                                            const float* __restrict__ Wk,
                                            const float* __restrict__ Wv,
                                            const float* __restrict__ Wo,
                                            f16* __restrict__ xh,
                                            f16* __restrict__ WqkT,
                                            f16* __restrict__ WvT,
                                            f16* __restrict__ WoT) {
    __shared__ f16 T[64][72];
    const int z = blockIdx.z;
    const int t = threadIdx.x;

    if (z == 3) {
        const int chunk = blockIdx.y * 16 + blockIdx.x;
        const float* src = x + (size_t)chunk * 16384;
        f16* dst = xh + (size_t)chunk * 16384;
#pragma unroll
        for (int it = 0; it < 16; it++) {
            const int i = it * 1024 + t * 4;
            float4 v = *(const float4*)(src + i);
            f16 o[4] = {(f16)v.x, (f16)v.y, (f16)v.z, (f16)v.w};
            *(ushort4*)(dst + i) = *(ushort4*)o;
        }
        return;
    }

    const float* W  = (z == 0) ? Wq : (z == 1) ? Wv : Wo;
    f16* WT = (z == 0) ? WqkT : (z == 1) ? WvT : WoT;
    const int k0 = blockIdx.x * 64, n0 = blockIdx.y * 64;
    const int r  = t >> 4;
    const int c4 = (t & 15) * 4;
#pragma unroll
    for (int rr = 0; rr < 64; rr += 16) {
        float4 w = *(const float4*)(W + (size_t)(k0 + rr + r) * HID + n0 + c4);
        if (z == 0) {
            float4 w2 = *(const float4*)(Wk + (size_t)(k0 + rr + r) * HID + n0 + c4);
            w.x -= w2.x; w.y -= w2.y; w.z -= w2.z; w.w -= w2.w;
        }
        T[c4 + 0][rr + r] = (f16)w.x;
        T[c4 + 1][rr + r] = (f16)w.y;
        T[c4 + 2][rr + r] = (f16)w.z;
        T[c4 + 3][rr + r] = (f16)w.w;
    }
    __syncthreads();
#pragma unroll
    for (int pp = 0; pp < 2; pp++) {
        const int nr = pp * 32 + (t >> 3);
        const int kc = (t & 7) * 8;
        *(uint4*)(WT + (size_t)(n0 + nr) * HID + k0 + kc) = *(uint4*)(&T[nr][kc]);
    }
}

// ---------------------------------------------------------------------------
// Fused projection GEMM (dif + vT): 128x64 tile, global_load_lds staging with
// XOR-octet swizzle. Epilogues via LDS bounce for coalesced stores.
// ---------------------------------------------------------------------------
__global__ __launch_bounds__(256, 4) void proj_gemm(const f16* __restrict__ A,
                                                    const f16* __restrict__ WqkT,
                                                    const f16* __restrict__ WvT,
                                                    const float* __restrict__ bq,
                                                    const float* __restrict__ bk,
                                                    const float* __restrict__ bv,
                                                    f16* __restrict__ dif,
                                                    f16* __restrict__ vT) {
    __shared__ f16 As[128 * 72];
    __shared__ f16 Bs[64 * 64];
    const int t = threadIdx.x;
    const int m0  = blockIdx.x * 128;
    const int n0g = blockIdx.y * 64;
    const bool isv = (n0g >= HID);
    const f16* BT = isv ? WvT : WqkT;
    const int n0 = n0g & (HID - 1);
    const int w = t >> 6, l = t & 63, quad = l >> 4, ln = l & 15;
    const int wm = w * 32;
    const int xk = ln & 7;

    const int srow8 = l >> 3;
    const int soct  = (l & 7) ^ srow8;
    const f16* pa = A  + (size_t)(m0 + w * 32 + srow8) * HID + soct * 8;
    const f16* pb = BT + (size_t)(n0 + w * 16 + srow8) * HID + soct * 8;

    f32x4 acc[2][4] = {};

    for (int k0 = 0; k0 < HID; k0 += 64) {
        __syncthreads();
#pragma unroll
        for (int c = 0; c < 4; c++)
            gld16(pa + (size_t)c * 8 * HID + k0, As + (w * 4 + c) * 512);
#pragma unroll
        for (int c = 0; c < 2; c++)
            gld16(pb + (size_t)c * 8 * HID + k0, Bs + (w * 2 + c) * 512);
        __syncthreads();

#pragma unroll
        for (int kh = 0; kh < 2; kh++) {
            f16x8 af[2], bf[4];
#pragma unroll
            for (int mt = 0; mt < 2; mt++) {
                const int row = wm + mt * 16 + ln;
                const int oct = (kh * 4 + quad) ^ xk;
                af[mt] = *(const f16x8*)(As + row * 64 + oct * 8);
            }
#pragma unroll
            for (int nt = 0; nt < 4; nt++) {
                const int row = nt * 16 + ln;
                const int oct = (kh * 4 + quad) ^ xk;
                bf[nt] = *(const f16x8*)(Bs + row * 64 + oct * 8);
            }
#pragma unroll
            for (int mt = 0; mt < 2; mt++)
#pragma unroll
                for (int nt = 0; nt < 4; nt++)
                    acc[mt][nt] = __builtin_amdgcn_mfma_f32_16x16x32_f16(
                        af[mt], bf[nt], acc[mt][nt], 0, 0, 0);
        }
    }

    __syncthreads();
    const int b_  = m0 >> 11;
    const int s0g = m0 & 2047;
    const int h_  = n0 >> 6;

    if (!isv) {
        float bb[4];
#pragma unroll
        for (int nt = 0; nt < 4; nt++) {
            const int nl = n0 + nt * 16 + ln;
            bb[nt] = bq[nl] - bk[nl];
        }
#pragma unroll
        for (int mt = 0; mt < 2; mt++)
#pragma unroll
            for (int nt = 0; nt < 4; nt++)
#pragma unroll
                for (int r = 0; r < 4; r++) {
                    const int sl = wm + mt * 16 + quad * 4 + r;
                    As[sl * 72 + nt * 16 + ln] = (f16)(acc[mt][nt][r] + bb[nt]);
                }
        __syncthreads();
        f16* base = dif + ((size_t)(b_ * 16 + h_) * SEQ + s0g) * 64;
        const int sl = t >> 1, eo = (t & 1) * 32;
#pragma unroll
        for (int i = 0; i < 4; i++)
            *(uint4*)(base + (size_t)sl * 64 + eo + i * 8) =
                *(uint4*)(&As[sl * 72 + eo + i * 8]);
    } else {
        float bb[4];
#pragma unroll
        for (int nt = 0; nt < 4; nt++)
            bb[nt] = bv[n0 + nt * 16 + ln];
#pragma unroll
        for (int mt = 0; mt < 2; mt++)
#pragma unroll
            for (int nt = 0; nt < 4; nt++)
#pragma unroll
                for (int r = 0; r < 4; r++) {
                    const int sl = wm + mt * 16 + quad * 4 + r;
                    As[(nt * 16 + ln) * 136 + sl] = (f16)(acc[mt][nt][r] + bb[nt]);
                }
        __syncthreads();
        const int eb = t >> 2, so = (t & 3) * 32;
        f16* base = vT + ((size_t)(b_ * 16 + h_) * 64 + eb) * SEQ + s0g + so;
#pragma unroll
        for (int i = 0; i < 4; i++)
            *(uint4*)(base + i * 8) = *(uint4*)(&As[eb * 136 + so + i * 8]);
    }
}

// ---------------------------------------------------------------------------
// Output GEMM: out = (C0+C1) @ WoT^T * 65536 + bo. 128x64 tile, dbuf LDS.
// ---------------------------------------------------------------------------
__global__ __launch_bounds__(256) void out_gemm(const f16* __restrict__ C0,
                                                const f16* __restrict__ C1,
                                                const f16* __restrict__ WoT,
                                                const float* __restrict__ bo,
                                                float* __restrict__ out) {
    __shared__ f16 As[2][128 * 72];
    __shared__ f16 Bs[2][64 * 72];
    const int t = threadIdx.x;
    const int m0 = blockIdx.x * 128, n0 = blockIdx.y * 64;
    const int w = t >> 6, l = t & 63, quad = l >> 4, ln = l & 15;
    const int wm = (w >> 1) * 64, wn = (w & 1) * 32;
    const int arow = t >> 1, ahalf = (t & 1) * 32;
    const int brow = t >> 2, boff = (t & 3) * 16;

    const f16* pa0 = C0  + (size_t)(m0 + arow) * HID + ahalf;
    const f16* pa1 = C1  + (size_t)(m0 + arow) * HID + ahalf;
    const f16* pb  = WoT + (size_t)(n0 + brow) * HID + boff;

    f16x8 a0 = *(const f16x8*)(pa0)      + *(const f16x8*)(pa1);
    f16x8 a1 = *(const f16x8*)(pa0 + 8)  + *(const f16x8*)(pa1 + 8);
    f16x8 a2 = *(const f16x8*)(pa0 + 16) + *(const f16x8*)(pa1 + 16);
    f16x8 a3 = *(const f16x8*)(pa0 + 24) + *(const f16x8*)(pa1 + 24);
    uint4 b0 = *(const uint4*)(pb), b1 = *(const uint4*)(pb + 8);

    f32x4 acc[4][2] = {};
    int buf = 0;

    for (int k0 = 0; k0 < HID; k0 += 64) {
        f16* da = As[buf] + arow * 72 + ahalf;
        *(f16x8*)(da)      = a0; *(f16x8*)(da + 8)  = a1;
        *(f16x8*)(da + 16) = a2; *(f16x8*)(da + 24) = a3;
        f16* db = Bs[buf] + brow * 72 + boff;
        *(uint4*)(db) = b0; *(uint4*)(db + 8) = b1;
        __syncthreads();
        if (k0 + 64 < HID) {
            const int kn = k0 + 64;
            a0 = *(const f16x8*)(pa0 + kn)      + *(const f16x8*)(pa1 + kn);
            a1 = *(const f16x8*)(pa0 + kn + 8)  + *(const f16x8*)(pa1 + kn + 8);
            a2 = *(const f16x8*)(pa0 + kn + 16) + *(const f16x8*)(pa1 + kn + 16);
            a3 = *(const f16x8*)(pa0 + kn + 24) + *(const f16x8*)(pa1 + kn + 24);
            b0 = *(const uint4*)(pb + kn); b1 = *(const uint4*)(pb + kn + 8);
        }
#pragma unroll
        for (int kh = 0; kh < 2; kh++) {
            f16x8 af[4], bf[2];
#pragma unroll
            for (int mt = 0; mt < 4; mt++)
                af[mt] = *(const f16x8*)(As[buf] + (wm + mt * 16 + ln) * 72 + kh * 32 + quad * 8);
#pragma unroll
            for (int nt = 0; nt < 2; nt++)
                bf[nt] = *(const f16x8*)(Bs[buf] + (wn + nt * 16 + ln) * 72 + kh * 32 + quad * 8);
#pragma unroll
            for (int mt = 0; mt < 4; mt++)
#pragma unroll
                for (int nt = 0; nt < 2; nt++)
                    acc[mt][nt] = __builtin_amdgcn_mfma_f32_16x16x32_f16(
                        af[mt], bf[nt], acc[mt][nt], 0, 0, 0);
        }
        buf ^= 1;
    }

#pragma unroll
    for (int mt = 0; mt < 4; mt++)
#pragma unroll
        for (int nt = 0; nt < 2; nt++) {
            const int n = n0 + wn + nt * 16 + ln;
            const float bb = bo[n];
            const int m_base = m0 + wm + mt * 16 + quad * 4;
#pragma unroll
            for (int r = 0; r < 4; r++)
                out[(size_t)(m_base + r) * HID + n] =
                    acc[mt][nt][r] * 65536.0f + bb;
        }
}

// ---------------------------------------------------------------------------
// fp16 MFMA attention R12: S^T = K.Q^T; P kept IN REGISTERS (S^T C-layout ==
// 16x16x16 A-layout) -> PV via v_mfma_f32_16x16x16f16, no Ps LDS round-trip.
// XCD-aware 1D grid: blk%8 pins all 32 blocks of a bh to one XCD (L2 local).
// LDS 27.6 KB; 1024 blocks = 4/CU.
// ---------------------------------------------------------------------------
__global__ __launch_bounds__(256, 4) void attn_f16(const f16* __restrict__ dif,
                                                   const f16* __restrict__ vT,
                                                   f16* __restrict__ ctx0,
                                                   f16* __restrict__ ctx1) {
    __shared__ f16 Qs[64 * 72];
    __shared__ f16 Ks[64 * 72];
    __shared__ f16 Vs[64 * 72];

    // XCD-local decode: bh = (blk&7)*4 + ((blk>>3)&3); 32 blocks/bh same blk%8
    const int blk = blockIdx.x;
    const int g   = blk >> 3;
    const int bh  = (blk & 7) * 4 + (g & 3);
    const int pq  = (g >> 2) & 15;
    const int ks  = g >> 6;

    f16* Cout = ks ? ctx1 : ctx0;
    const f16* D  = dif + (size_t)bh * SEQ * 64;
    const f16* VT = vT  + (size_t)bh * 64 * SEQ;
    const int b = bh >> 4, h = bh & 15;
    const int t = threadIdx.x, w = t >> 6, l = t & 63, quad = l >> 4, ln = l & 15;
    const int qh = w >> 1, jh = w & 1;
    const int ve = t >> 2, vc = (t & 3) * 16;

    for (int half = 0; half < 2; half++) {
        const int qt = half ? (31 - pq) : pq;
        const int i0 = qt * 64;
        __syncthreads();   // prior half's LDS use complete

        // stage Q tile, pull this wave's A-frags (rows qh*32..) to regs
#pragma unroll
        for (int rr = 0; rr < 2; rr++) {
            const int o = rr * 2048 + t * 8;
            uint4 v = *(const uint4*)(D + i0 * 64 + o);
            *(uint4*)(Qs + (o >> 6) * 72 + (o & 63)) = v;
        }
        __syncthreads();
        f16x8 aq[2][2];   // [mt][kh]
#pragma unroll
        for (int mt = 0; mt < 2; mt++)
#pragma unroll
            for (int kh = 0; kh < 2; kh++)
                aq[mt][kh] = *(const f16x8*)(Qs + (qh * 32 + mt * 16 + ln) * 72
                                             + kh * 32 + quad * 8);

        f32x4 acc[2][4] = {};   // [mt(q)][nte(e)]
        const int kt0 = qt + ks;

        uint4 kr0, kr1, vr0, vr1;
        if (kt0 < 32) {
            const int j0 = kt0 * 64;
            kr0 = *(const uint4*)(D + j0 * 64 + t * 8);
            kr1 = *(const uint4*)(D + j0 * 64 + 2048 + t * 8);
            vr0 = *(const uint4*)(VT + (size_t)ve * SEQ + j0 + vc);
            vr1 = *(const uint4*)(VT + (size_t)ve * SEQ + j0 + vc + 8);
        }

        for (int kt = kt0; kt < 32; kt += 2) {
            const int j0 = kt * 64;
            __syncthreads();

            {
                const int o0 = t * 8, o1 = 2048 + t * 8;
                *(uint4*)(Ks + (o0 >> 6) * 72 + (o0 & 63)) = kr0;
                *(uint4*)(Ks + (o1 >> 6) * 72 + (o1 & 63)) = kr1;
                *(uint4*)(Vs + ve * 72 + vc)     = vr0;
                *(uint4*)(Vs + ve * 72 + vc + 8) = vr1;
            }
            __syncthreads();

            if (kt + 2 < 32) {
                const int j2 = (kt + 2) * 64;
                kr0 = *(const uint4*)(D + j2 * 64 + t * 8);
                kr1 = *(const uint4*)(D + j2 * 64 + 2048 + t * 8);
                vr0 = *(const uint4*)(VT + (size_t)ve * SEQ + j2 + vc);
                vr1 = *(const uint4*)(VT + (size_t)ve * SEQ + j2 + vc + 8);
            }

            // ---- S^T = K . Q^T  (32 j-rows x 32 q-cols per wave) ----
            f32x4 st[2][2] = {};   // [ntj][mt]
#pragma unroll
            for (int kh = 0; kh < 2; kh++)
#pragma unroll
                for (int nt = 0; nt < 2; nt++) {
                    f16x8 ak = *(const f16x8*)(Ks + (jh * 32 + nt * 16 + ln) * 72
                                               + kh * 32 + quad * 8);
#pragma unroll
                    for (int mt = 0; mt < 2; mt++)
                        st[nt][mt] = __builtin_amdgcn_mfma_f32_16x16x32_f16(
                            ak, aq[mt][kh], st[nt][mt], 0, 0, 0);
                }

            // ---- P in registers: C-layout(q=ln, j=quad*4+r) == 16x16x16 A-layout
            const bool full = (kt > qt);
            f16x4 pf[2][2];   // [ntj][mt]
#pragma unroll
            for (int nt = 0; nt < 2; nt++)
#pragma unroll
                for (int mt = 0; mt < 2; mt++) {
                    const int gi = i0 + qh * 32 + mt * 16 + ln;
#pragma unroll
                    for (int r = 0; r < 4; r++) {
                        const int gj = j0 + jh * 32 + nt * 16 + quad * 4 + r;
                        float p = (full || (gj > gi))
                                      ? fminf(__expf(fmaf(st[nt][mt][r], -0.5f,
                                                          -11.090354888959125f)),
                                              60000.0f)
                                      : 0.0f;
                        pf[nt][mt][r] = (f16)p;
                    }
                }

            // ---- ctx += P @ V via 16x16x16 (B-frag: V[j=quad*4+i][e=ln]) ----
#pragma unroll
            for (int nt = 0; nt < 2; nt++)
#pragma unroll
                for (int nte = 0; nte < 4; nte++) {
                    f16x4 bv = *(const f16x4*)(Vs + (nte * 16 + ln) * 72
                                               + jh * 32 + nt * 16 + quad * 4);
#pragma unroll
                    for (int mt = 0; mt < 2; mt++)
                        acc[mt][nte] = __builtin_amdgcn_mfma_f32_16x16x16f16(
                            pf[nt][mt], bv, acc[mt][nte], 0, 0, 0);
                }
        }

        // ---- cross-jh reduction via Qs (free now) + store partial ctx ----
        __syncthreads();   // all waves done with Ks/Vs reads & Qs frags
        if (jh == 1) {
#pragma unroll
            for (int mt = 0; mt < 2; mt++)
#pragma unroll
                for (int nte = 0; nte < 4; nte++)
#pragma unroll
                    for (int r = 0; r < 4; r++)
                        Qs[(qh * 32 + mt * 16 + quad * 4 + r) * 72 + nte * 16 + ln] =
                            (f16)acc[mt][nte][r];
        }
        __syncthreads();
        if (jh == 0) {
#pragma unroll
            for (int mt = 0; mt < 2; mt++)
#pragma unroll
                for (int nte = 0; nte < 4; nte++)
#pragma unroll
                    for (int r = 0; r < 4; r++) {
                        const int iloc = qh * 32 + mt * 16 + quad * 4 + r;
                        float v = acc[mt][nte][r]
                                + (float)Qs[iloc * 72 + nte * 16 + ln];
                        Cout[(size_t)(b * SEQ + i0 + iloc) * HID + h * 64
                             + nte * 16 + ln] = (f16)v;
                    }
        }
    }
}

// ---------------------------------------------------------------------------
extern "C" void kernel_launch(void* const* d_in, const int* in_sizes, int n_in,
                              void* d_out, int out_size, void* d_ws, size_t ws_size,
                              hipStream_t stream) {
    const float* x  = (const float*)d_in[0];
    const float* Wq = (const float*)d_in[1];
    const float* bq = (const float*)d_in[2];
    const float* Wk = (const float*)d_in[3];
    const float* bk = (const float*)d_in[4];
    const float* Wv = (const float*)d_in[5];
    const float* bv = (const float*)d_in[6];
    const float* Wo = (const float*)d_in[7];
    const float* bo = (const float*)d_in[8];
    float* out = (float*)d_out;

    char* ws = (char*)d_ws;
    f16* xh   = (f16*)(ws);               // 8 MB  [M][1024]
    f16* WqkT = (f16*)(ws + (8 << 20));   // 2 MB  [n][k]
    f16* WvT  = (f16*)(ws + (10 << 20));  // 2 MB
    f16* WoT  = (f16*)(ws + (12 << 20));  // 2 MB
    f16* dif  = (f16*)(ws + (14 << 20));  // 8 MB  [bh][s][64]
    f16* vT   = (f16*)(ws + (22 << 20));  // 8 MB  [bh][e][s]
    f16* ctx0 = (f16*)(ws + (30 << 20));  // 8 MB  partial (x 2^-16)
    f16* ctx1 = (f16*)(ws + (38 << 20));  // 8 MB  partial

    prep<<<dim3(16, 16, 4), 256, 0, stream>>>(x, Wq, Wk, Wv, Wo,
                                              xh, WqkT, WvT, WoT);
    proj_gemm<<<dim3(MTOT / 128, 32), 256, 0, stream>>>(xh, WqkT, WvT,
                                                        bq, bk, bv, dif, vT);
    attn_f16<<<1024, 256, 0, stream>>>(dif, vT, ctx0, ctx1);
    out_gemm<<<dim3(MTOT / 128, 16), 256, 0, stream>>>(ctx0, ctx1, WoT, bo, out);
}